// Round 6
// baseline (425.059 us; speedup 1.0000x reference)
//
#include <hip/hip_runtime.h>
#include <hip/hip_bf16.h>
#include <hip/hip_fp16.h>

typedef unsigned int uint32;
typedef unsigned short u16;

#define TOK 1024
#define HID 2048
#define NEXP 64
#define TOPK 8
#define IMED 768
#define IMED2 1536

typedef __attribute__((ext_vector_type(8))) _Float16 half8;
typedef __attribute__((ext_vector_type(4))) float f32x4;

static __device__ __forceinline__ uint32 pack2(float a, float b) {
  union { _Float16 h[2]; uint32 u; } p;
  p.h[0] = (_Float16)a; p.h[1] = (_Float16)b;
  return p.u;
}
static __device__ __forceinline__ u16 f2h(float a) {
  union { _Float16 h; u16 u; } p;
  p.h = (_Float16)a;
  return p.u;
}

// ---------------- router: logits -> top8 -> renorm; emits xh + cnt ----------
__global__ __launch_bounds__(256) void router_kernel(
    const float* __restrict__ x, const float* __restrict__ gw,
    int* __restrict__ topk_id, float* __restrict__ topk_w,
    u16* __restrict__ xh, int* __restrict__ cnt) {
  int t0 = blockIdx.x << 2;
  __shared__ float part[4][NEXP][5];
  int tid = threadIdx.x;
  int e = tid & 63, p = tid >> 6;
  const float* gwp = gw + (size_t)e * HID + (p << 9);
  const float* xp = x + (size_t)t0 * HID + (p << 9);
  float acc[4] = {0.f, 0.f, 0.f, 0.f};
  for (int i = 0; i < 128; i++) {
    float4 w = ((const float4*)gwp)[i];
    #pragma unroll
    for (int t = 0; t < 4; t++) {
      float4 xv = *(const float4*)(xp + (size_t)t * HID + (i << 2));
      acc[t] += w.x * xv.x + w.y * xv.y + w.z * xv.z + w.w * xv.w;
    }
  }
  #pragma unroll
  for (int t = 0; t < 4; t++) part[p][e][t] = acc[t];
  // emit xh for these 4 tokens
  for (int i = tid; i < 2048; i += 256) {
    int r = i >> 9;
    int c = i & 511;
    float4 v = *(const float4*)(x + (size_t)(t0 + r) * HID + (c << 2));
    uint2 hp;
    hp.x = pack2(v.x, v.y);
    hp.y = pack2(v.z, v.w);
    *(uint2*)(xh + (size_t)(t0 + r) * HID + (c << 2)) = hp;
  }
  __syncthreads();
  int wv = tid >> 6, l = tid & 63;
  int t = t0 + wv;
  float lg = part[0][l][wv] + part[1][l][wv] + part[2][l][wv] + part[3][l][wv];
  float m = lg;
  #pragma unroll
  for (int d = 1; d < 64; d <<= 1) m = fmaxf(m, __shfl_xor(m, d));
  float v = __expf(lg - m);
  float w8[TOPK]; int i8[TOPK]; float wsum = 0.f;
  #pragma unroll
  for (int k = 0; k < TOPK; k++) {
    float bv = v; int bi = l;
    #pragma unroll
    for (int d = 1; d < 64; d <<= 1) {
      float ov = __shfl_xor(bv, d);
      int oi = __shfl_xor(bi, d);
      if (ov > bv || (ov == bv && oi < bi)) { bv = ov; bi = oi; }
    }
    w8[k] = bv; i8[k] = bi; wsum += bv;
    if (l == bi) v = -1.f;
  }
  if (l == 0) {
    float rinv = 1.f / wsum;
    #pragma unroll
    for (int k = 0; k < TOPK; k++) {
      topk_id[t * TOPK + k] = i8[k];
      topk_w[t * TOPK + k] = w8[k] * rinv;
      atomicAdd(&cnt[i8[k]], 1);
    }
  }
}

// ---------------- parallel per-expert scatter (64 blocks) ----------------
__global__ __launch_bounds__(256) void scatter_kernel(
    const int* __restrict__ topk_id, const float* __restrict__ topk_w,
    const int* __restrict__ cnt, int* __restrict__ off,
    int* __restrict__ row_tok, float* __restrict__ row_w) {
  int e = blockIdx.x;
  __shared__ int sbase;
  __shared__ int scur;
  int tid = threadIdx.x;
  if (tid < 64) {
    int c = cnt[tid];
    int xv = c;
    #pragma unroll
    for (int d = 1; d < 64; d <<= 1) {
      int y = __shfl_up(xv, d);
      if (tid >= d) xv += y;
    }
    if (tid == e) { sbase = xv - c; off[e] = xv - c; }
    if (tid == 0) scur = 0;
  }
  __syncthreads();
  int base = sbase;
  for (int i = tid; i < TOK * TOPK; i += 256) {
    if (topk_id[i] == e) {
      int p = atomicAdd(&scur, 1);
      row_tok[base + p] = i >> 3;
      row_w[base + p] = topk_w[i];
    }
  }
}

// ---------------- grouped gate_up GEMM + fused SwiGLU ----------------
// BM=256, BN=96 gate + 96 up, BK=32, 512 threads (8 waves 4m x 2n)
// single LDS buffer, 2-deep register prefetch, XCD-bijective block remap
#define GU_LOAD(S)                                                        \
  {                                                                       \
    const uint4* p_ = (const uint4*)xa;                                   \
    qa0_##S = p_[0]; qa1_##S = p_[1];                                     \
    xa += 32;                                                             \
    if (bact) {                                                           \
      w0_##S = *(const float4*)(wb);                                      \
      w1_##S = *(const float4*)(wb + IMED2);                              \
      w2_##S = *(const float4*)(wb + 2 * IMED2);                          \
      w3_##S = *(const float4*)(wb + 3 * IMED2);                          \
    }                                                                     \
    wb += (size_t)32 * IMED2;                                             \
  }

#define GU_STORE(S)                                                       \
  {                                                                       \
    char* A_ = AsB + arow * 80;                                           \
    int g0 = aseg << 1;                                                   \
    *(uint4*)(A_ + (((g0 + 0) ^ axr) << 4)) = qa0_##S;                    \
    *(uint4*)(A_ + (((g0 + 1) ^ axr) << 4)) = qa1_##S;                    \
    if (bact) {                                                           \
      float c0v[4] = {w0_##S.x, w0_##S.y, w0_##S.z, w0_##S.w};            \
      float c1v[4] = {w1_##S.x, w1_##S.y, w1_##S.z, w1_##S.w};            \
      float c2v[4] = {w2_##S.x, w2_##S.y, w2_##S.z, w2_##S.w};            \
      float c3v[4] = {w3_##S.x, w3_##S.y, w3_##S.z, w3_##S.w};            \
      int kg = kq >> 1, kb = (kq & 1) << 3;                               \
      _Pragma("unroll")                                                   \
      for (int cc = 0; cc < 4; cc++) {                                    \
        int br = brbase + cc;                                             \
        uint2 pv;                                                         \
        pv.x = pack2(c0v[cc], c1v[cc]);                                   \
        pv.y = pack2(c2v[cc], c3v[cc]);                                   \
        *(uint2*)(BsB + br * 80 + (((kg ^ (br >> 2)) & 3) << 4) + kb) = pv; \
      }                                                                   \
    }                                                                     \
  }

#define GU_COMPUTE()                                                      \
  {                                                                       \
    half8 af[4];                                                          \
    _Pragma("unroll")                                                     \
    for (int mi = 0; mi < 4; mi++) {                                      \
      int r = (wm << 6) + (mi << 4) + fr;                                 \
      af[mi] = *(half8*)(AsB + r * 80 + (((hi ^ (r >> 2)) & 3) << 4));    \
    }                                                                     \
    _Pragma("unroll")                                                     \
    for (int ni = 0; ni < 3; ni++) {                                      \
      int ng = (wn * 48) + (ni << 4) + fr;                                \
      int nu = ng + 96;                                                   \
      half8 bg = *(half8*)(BsB + ng * 80 + (((hi ^ (ng >> 2)) & 3) << 4)); \
      half8 bu = *(half8*)(BsB + nu * 80 + (((hi ^ (nu >> 2)) & 3) << 4)); \
      _Pragma("unroll")                                                   \
      for (int mi = 0; mi < 4; mi++) {                                    \
        accg[mi][ni] = __builtin_amdgcn_mfma_f32_16x16x32_f16(af[mi], bg, accg[mi][ni], 0, 0, 0); \
        accu[mi][ni] = __builtin_amdgcn_mfma_f32_16x16x32_f16(af[mi], bu, accu[mi][ni], 0, 0, 0); \
      }                                                                   \
    }                                                                     \
  }

__global__ __launch_bounds__(512, 2) void gateup_kernel(
    const u16* __restrict__ xh, const float* __restrict__ Wgu,
    const int* __restrict__ off, const int* __restrict__ cnt,
    const int* __restrict__ row_tok, u16* __restrict__ act) {
  int bid = blockIdx.x;                 // 512 blocks
  int xcd = bid & 7, s2 = bid >> 3;
  int e = xcd + ((s2 & 7) << 3);
  int slab = s2 >> 3;                   // 0..7
  int r0 = off[e];
  int ne = cnt[e];
  int c0 = slab * 96;

  __shared__ __align__(16) char AsB[256 * 80];
  __shared__ __align__(16) char BsB[192 * 80];

  int tid = threadIdx.x;
  int lane = tid & 63;
  int wid = tid >> 6;
  int wm = wid >> 1, wn = wid & 1;
  int fr = lane & 15, hi = lane >> 4;

  int arow = tid >> 1, aseg = tid & 1;
  int tok = row_tok[r0 + ((arow < ne) ? arow : 0)];
  const u16* xa = xh + (size_t)tok * HID + (aseg << 4);
  int axr = (arow >> 2) & 3;

  bool bact = tid < 384;
  int cg = tid % 24, h = (tid / 24) & 1, kq = tid / 48;
  int bcol = cg << 2;
  int gc = h ? (IMED + c0 + bcol) : (c0 + bcol);
  const float* wb = Wgu + (size_t)e * ((size_t)HID * IMED2) + (size_t)(kq << 2) * IMED2 + gc;
  int brbase = 96 * h + bcol;

  f32x4 accg[4][3], accu[4][3];
  #pragma unroll
  for (int a = 0; a < 4; a++)
    #pragma unroll
    for (int b = 0; b < 3; b++) { accg[a][b] = (f32x4)0.f; accu[a][b] = (f32x4)0.f; }

  uint4 qa0_0, qa1_0, qa0_1, qa1_1;
  float4 w0_0, w1_0, w2_0, w3_0, w0_1, w1_1, w2_1, w3_1;

  const int NK = HID / 32;  // 64 (even)
  GU_LOAD(0);   // tile 0
  GU_LOAD(1);   // tile 1
  GU_STORE(0);  // tile 0
  GU_LOAD(0);   // tile 2
  __syncthreads();

  for (int t = 0; t < NK; t += 2) {
    GU_COMPUTE();                       // tile t
    __syncthreads();
    GU_STORE(1);                        // tile t+1
    if (t + 3 < NK) GU_LOAD(1);         // tile t+3
    __syncthreads();
    GU_COMPUTE();                       // tile t+1
    __syncthreads();
    if (t + 2 < NK) {
      GU_STORE(0);                      // tile t+2
      if (t + 4 < NK) GU_LOAD(0);       // tile t+4
      __syncthreads();
    }
  }

  #pragma unroll
  for (int mi = 0; mi < 4; mi++) {
    #pragma unroll
    for (int ni = 0; ni < 3; ni++) {
      int col = c0 + wn * 48 + (ni << 4) + fr;
      #pragma unroll
      for (int r = 0; r < 4; r++) {
        int rr = (wm << 6) + (mi << 4) + (hi << 2) + r;
        if (rr < ne) {
          float g = accg[mi][ni][r];
          float u = accu[mi][ni][r];
          float s = g / (1.f + __expf(-g)) * u;
          act[(size_t)(r0 + rr) * IMED + col] = f2h(s);
        }
      }
    }
  }
}

// ---------------- grouped down GEMM + weighted scatter-add ----------------
// BM=256, BN=256, BK=32, 512 threads (8 waves 4m x 2n), 2-deep prefetch
#define DN_LOAD(S)                                                        \
  {                                                                       \
    const uint4* p_ = (const uint4*)ap;                                   \
    qa0_##S = p_[0]; qa1_##S = p_[1];                                     \
    ap += 32;                                                             \
    w0_##S = *(const float4*)(wb);                                        \
    w1_##S = *(const float4*)(wb + HID);                                  \
    w2_##S = *(const float4*)(wb + 2 * HID);                              \
    w3_##S = *(const float4*)(wb + 3 * HID);                              \
    wb += (size_t)32 * HID;                                               \
  }

#define DN_STORE(S)                                                       \
  {                                                                       \
    char* A_ = AsB + arow * 80;                                           \
    int g0 = aseg << 1;                                                   \
    *(uint4*)(A_ + (((g0 + 0) ^ axr) << 4)) = qa0_##S;                    \
    *(uint4*)(A_ + (((g0 + 1) ^ axr) << 4)) = qa1_##S;                    \
    float c0v[4] = {w0_##S.x, w0_##S.y, w0_##S.z, w0_##S.w};              \
    float c1v[4] = {w1_##S.x, w1_##S.y, w1_##S.z, w1_##S.w};              \
    float c2v[4] = {w2_##S.x, w2_##S.y, w2_##S.z, w2_##S.w};              \
    float c3v[4] = {w3_##S.x, w3_##S.y, w3_##S.z, w3_##S.w};              \
    int kg = kq >> 1, kb = (kq & 1) << 3;                                 \
    _Pragma("unroll")                                                     \
    for (int cc = 0; cc < 4; cc++) {                                      \
      int br = bcol + cc;                                                 \
      uint2 pv;                                                           \
      pv.x = pack2(c0v[cc], c1v[cc]);                                     \
      pv.y = pack2(c2v[cc], c3v[cc]);                                     \
      *(uint2*)(BsB + br * 80 + (((kg ^ (br >> 2)) & 3) << 4) + kb) = pv; \
    }                                                                     \
  }

#define DN_COMPUTE()                                                      \
  {                                                                       \
    half8 af[4];                                                          \
    _Pragma("unroll")                                                     \
    for (int mi = 0; mi < 4; mi++) {                                      \
      int r = (wm << 6) + (mi << 4) + fr;                                 \
      af[mi] = *(half8*)(AsB + r * 80 + (((hi ^ (r >> 2)) & 3) << 4));    \
    }                                                                     \
    _Pragma("unroll")                                                     \
    for (int ni = 0; ni < 8; ni++) {                                      \
      int n = (wn << 7) + (ni << 4) + fr;                                 \
      half8 bf_ = *(half8*)(BsB + n * 80 + (((hi ^ (n >> 2)) & 3) << 4)); \
      _Pragma("unroll")                                                   \
      for (int mi = 0; mi < 4; mi++)                                      \
        acc[mi][ni] = __builtin_amdgcn_mfma_f32_16x16x32_f16(af[mi], bf_, acc[mi][ni], 0, 0, 0); \
    }                                                                     \
  }

__global__ __launch_bounds__(512, 2) void down_kernel(
    const u16* __restrict__ act, const float* __restrict__ Wd,
    const int* __restrict__ off, const int* __restrict__ cnt,
    const int* __restrict__ row_tok, const float* __restrict__ row_w,
    float* __restrict__ out) {
  int bid = blockIdx.x;                 // 512 blocks
  int xcd = bid & 7, s2 = bid >> 3;
  int e = xcd + ((s2 & 7) << 3);
  int slab = s2 >> 3;
  int r0 = off[e];
  int ne = cnt[e];
  int n0 = slab << 8;

  __shared__ __align__(16) char AsB[256 * 80];
  __shared__ __align__(16) char BsB[256 * 80];

  int tid = threadIdx.x;
  int lane = tid & 63;
  int wid = tid >> 6;
  int wm = wid >> 1, wn = wid & 1;
  int fr = lane & 15, hi = lane >> 4;

  int arow = tid >> 1, aseg = tid & 1;
  const u16* ap = act + (size_t)(r0 + ((arow < ne) ? arow : 0)) * IMED + (aseg << 4);
  int axr = (arow >> 2) & 3;

  int cq = tid & 63, kq = tid >> 6;
  int bcol = cq << 2;
  const float* wb = Wd + (size_t)e * ((size_t)IMED * HID) + (size_t)(kq << 2) * HID + n0 + bcol;

  f32x4 acc[4][8];
  #pragma unroll
  for (int a = 0; a < 4; a++)
    #pragma unroll
    for (int b = 0; b < 8; b++) acc[a][b] = (f32x4)0.f;

  uint4 qa0_0, qa1_0, qa0_1, qa1_1;
  float4 w0_0, w1_0, w2_0, w3_0, w0_1, w1_1, w2_1, w3_1;

  const int NK = IMED / 32;  // 24 (even)
  DN_LOAD(0);
  DN_LOAD(1);
  DN_STORE(0);
  DN_LOAD(0);
  __syncthreads();

  for (int t = 0; t < NK; t += 2) {
    DN_COMPUTE();
    __syncthreads();
    DN_STORE(1);
    if (t + 3 < NK) DN_LOAD(1);
    __syncthreads();
    DN_COMPUTE();
    __syncthreads();
    if (t + 2 < NK) {
      DN_STORE(0);
      if (t + 4 < NK) DN_LOAD(0);
      __syncthreads();
    }
  }

  #pragma unroll
  for (int mi = 0; mi < 4; mi++) {
    #pragma unroll
    for (int r = 0; r < 4; r++) {
      int rr = (wm << 6) + (mi << 4) + (hi << 2) + r;
      if (rr < ne) {
        float w = row_w[r0 + rr];
        int t = row_tok[r0 + rr];
        #pragma unroll
        for (int ni = 0; ni < 8; ni++) {
          int col = n0 + (wn << 7) + (ni << 4) + fr;
          unsafeAtomicAdd(&out[(size_t)t * HID + col], acc[mi][ni][r] * w);
        }
      }
    }
  }
}

// ---------------- launch ----------------
extern "C" void kernel_launch(void* const* d_in, const int* in_sizes, int n_in,
                              void* d_out, int out_size, void* d_ws, size_t ws_size,
                              hipStream_t stream) {
  const float* x = (const float*)d_in[0];
  const float* gw = (const float*)d_in[1];
  const float* wgu = (const float*)d_in[2];
  const float* wd = (const float*)d_in[3];
  float* out = (float*)d_out;
  char* ws = (char*)d_ws;

  int* cnt = (int*)(ws + 0);                    // 64 ints
  int* off = (int*)(ws + 512);                  // 64 ints
  int* topk_id = (int*)(ws + 1024);
  float* topk_w = (float*)(ws + 1024 + 32768);
  int* row_tok = (int*)(ws + 1024 + 65536);
  float* row_w = (float*)(ws + 1024 + 98304);
  u16* act = (u16*)(ws + 135168);                                  // 12.6 MB
  u16* xh = (u16*)(ws + 135168 + (size_t)TOK * TOPK * IMED * 2);   // 4.2 MB

  hipMemsetAsync(cnt, 0, 256, stream);
  router_kernel<<<TOK / 4, 256, 0, stream>>>(x, gw, topk_id, topk_w, xh, cnt);
  scatter_kernel<<<NEXP, 256, 0, stream>>>(topk_id, topk_w, cnt, off, row_tok, row_w);
  hipMemsetAsync(out, 0, (size_t)TOK * HID * sizeof(float), stream);
  gateup_kernel<<<512, 512, 0, stream>>>(xh, wgu, off, cnt, row_tok, act);
  down_kernel<<<512, 512, 0, stream>>>(act, wd, off, cnt, row_tok, row_w, out);
}

// Round 7
// 398.399 us; speedup vs baseline: 1.0669x; 1.0669x over previous
//
#include <hip/hip_runtime.h>
#include <hip/hip_bf16.h>
#include <hip/hip_fp16.h>

typedef unsigned int uint32;
typedef unsigned short u16;

#define TOK 1024
#define HID 2048
#define NEXP 64
#define TOPK 8
#define IMED 768
#define IMED2 1536

typedef __attribute__((ext_vector_type(8))) _Float16 half8;
typedef __attribute__((ext_vector_type(4))) float f32x4;

static __device__ __forceinline__ uint32 pack2(float a, float b) {
  union { _Float16 h[2]; uint32 u; } p;
  p.h[0] = (_Float16)a; p.h[1] = (_Float16)b;
  return p.u;
}
static __device__ __forceinline__ u16 f2h(float a) {
  union { _Float16 h; u16 u; } p;
  p.h = (_Float16)a;
  return p.u;
}

// ---------------- router: logits -> top8 -> renorm; emits xh + cnt ----------
__global__ __launch_bounds__(256) void router_kernel(
    const float* __restrict__ x, const float* __restrict__ gw,
    int* __restrict__ topk_id, float* __restrict__ topk_w,
    u16* __restrict__ xh, int* __restrict__ cnt) {
  int t0 = blockIdx.x << 2;
  __shared__ float part[4][NEXP][5];
  int tid = threadIdx.x;
  int e = tid & 63, p = tid >> 6;
  const float* gwp = gw + (size_t)e * HID + (p << 9);
  const float* xp = x + (size_t)t0 * HID + (p << 9);
  float acc[4] = {0.f, 0.f, 0.f, 0.f};
  for (int i = 0; i < 128; i++) {
    float4 w = ((const float4*)gwp)[i];
    #pragma unroll
    for (int t = 0; t < 4; t++) {
      float4 xv = *(const float4*)(xp + (size_t)t * HID + (i << 2));
      acc[t] += w.x * xv.x + w.y * xv.y + w.z * xv.z + w.w * xv.w;
    }
  }
  #pragma unroll
  for (int t = 0; t < 4; t++) part[p][e][t] = acc[t];
  for (int i = tid; i < 2048; i += 256) {
    int r = i >> 9;
    int c = i & 511;
    float4 v = *(const float4*)(x + (size_t)(t0 + r) * HID + (c << 2));
    uint2 hp;
    hp.x = pack2(v.x, v.y);
    hp.y = pack2(v.z, v.w);
    *(uint2*)(xh + (size_t)(t0 + r) * HID + (c << 2)) = hp;
  }
  __syncthreads();
  int wv = tid >> 6, l = tid & 63;
  int t = t0 + wv;
  float lg = part[0][l][wv] + part[1][l][wv] + part[2][l][wv] + part[3][l][wv];
  float m = lg;
  #pragma unroll
  for (int d = 1; d < 64; d <<= 1) m = fmaxf(m, __shfl_xor(m, d));
  float v = __expf(lg - m);
  float w8[TOPK]; int i8[TOPK]; float wsum = 0.f;
  #pragma unroll
  for (int k = 0; k < TOPK; k++) {
    float bv = v; int bi = l;
    #pragma unroll
    for (int d = 1; d < 64; d <<= 1) {
      float ov = __shfl_xor(bv, d);
      int oi = __shfl_xor(bi, d);
      if (ov > bv || (ov == bv && oi < bi)) { bv = ov; bi = oi; }
    }
    w8[k] = bv; i8[k] = bi; wsum += bv;
    if (l == bi) v = -1.f;
  }
  if (l == 0) {
    float rinv = 1.f / wsum;
    #pragma unroll
    for (int k = 0; k < TOPK; k++) {
      topk_id[t * TOPK + k] = i8[k];
      topk_w[t * TOPK + k] = w8[k] * rinv;
      atomicAdd(&cnt[i8[k]], 1);
    }
  }
}

// ---------------- parallel per-expert scatter (64 blocks) + inverse map ----
__global__ __launch_bounds__(256) void scatter_kernel(
    const int* __restrict__ topk_id, const float* __restrict__ topk_w,
    const int* __restrict__ cnt, int* __restrict__ off,
    int* __restrict__ row_tok, float* __restrict__ row_w,
    int* __restrict__ inv) {
  int e = blockIdx.x;
  __shared__ int sbase;
  __shared__ int scur;
  int tid = threadIdx.x;
  if (tid < 64) {
    int c = cnt[tid];
    int xv = c;
    #pragma unroll
    for (int d = 1; d < 64; d <<= 1) {
      int y = __shfl_up(xv, d);
      if (tid >= d) xv += y;
    }
    if (tid == e) { sbase = xv - c; off[e] = xv - c; }
    if (tid == 0) scur = 0;
  }
  __syncthreads();
  int base = sbase;
  for (int i = tid; i < TOK * TOPK; i += 256) {
    if (topk_id[i] == e) {
      int p = atomicAdd(&scur, 1);
      row_tok[base + p] = i >> 3;
      row_w[base + p] = topk_w[i];
      inv[i] = base + p;
    }
  }
}

// ---------------- grouped gate_up GEMM + fused SwiGLU (R5 schedule) --------
// BM=256, BN=96 gate + 96 up, BK=32, 512 threads (8 waves 4m x 2n)
// single LDS buffer, 1-deep register prefetch, XCD-bijective block remap
__global__ __launch_bounds__(512, 2) void gateup_kernel(
    const u16* __restrict__ xh, const float* __restrict__ Wgu,
    const int* __restrict__ off, const int* __restrict__ cnt,
    const int* __restrict__ row_tok, u16* __restrict__ act) {
  int bid = blockIdx.x;                 // 512 blocks
  int xcd = bid & 7, s2 = bid >> 3;
  int e = xcd + ((s2 & 7) << 3);        // all slabs of expert e on one XCD
  int slab = s2 >> 3;                   // 0..7
  int r0 = off[e];
  int ne = cnt[e];
  int c0 = slab * 96;

  __shared__ __align__(16) char AsB[256 * 80];  // 20KB
  __shared__ __align__(16) char BsB[192 * 80];  // 15KB

  int tid = threadIdx.x;
  int lane = tid & 63;
  int wid = tid >> 6;
  int wm = wid >> 1, wn = wid & 1;      // 4m x 2n
  int fr = lane & 15, hi = lane >> 4;

  int arow = tid >> 1, aseg = tid & 1;
  int tok = row_tok[r0 + ((arow < ne) ? arow : 0)];
  const u16* xa = xh + (size_t)tok * HID + (aseg << 4);
  int axr = (arow >> 2) & 3;

  bool bact = tid < 384;
  int cg = tid % 24, h = (tid / 24) & 1, kq = tid / 48;  // kq 0..7
  int bcol = cg << 2;
  int gc = h ? (IMED + c0 + bcol) : (c0 + bcol);
  const float* wb = Wgu + (size_t)e * ((size_t)HID * IMED2) + (size_t)(kq << 2) * IMED2 + gc;
  int brbase = 96 * h + bcol;

  f32x4 accg[4][3], accu[4][3];
  #pragma unroll
  for (int a = 0; a < 4; a++)
    #pragma unroll
    for (int b = 0; b < 3; b++) { accg[a][b] = (f32x4)0.f; accu[a][b] = (f32x4)0.f; }

  uint4 qa0, qa1;
  float4 w0, w1, w2, w3;
  auto LOADT = [&]() {
    const uint4* p = (const uint4*)xa;
    qa0 = p[0]; qa1 = p[1];
    xa += 32;
    if (bact) {
      w0 = *(const float4*)(wb);
      w1 = *(const float4*)(wb + IMED2);
      w2 = *(const float4*)(wb + 2 * IMED2);
      w3 = *(const float4*)(wb + 3 * IMED2);
    }
    wb += (size_t)32 * IMED2;
  };
  auto STORET = [&]() {
    char* A_ = AsB + arow * 80;
    int g0 = aseg << 1;
    *(uint4*)(A_ + (((g0 + 0) ^ axr) << 4)) = qa0;
    *(uint4*)(A_ + (((g0 + 1) ^ axr) << 4)) = qa1;
    if (bact) {
      float c0v[4] = {w0.x, w0.y, w0.z, w0.w};
      float c1v[4] = {w1.x, w1.y, w1.z, w1.w};
      float c2v[4] = {w2.x, w2.y, w2.z, w2.w};
      float c3v[4] = {w3.x, w3.y, w3.z, w3.w};
      int kg = kq >> 1, kb = (kq & 1) << 3;
      #pragma unroll
      for (int cc = 0; cc < 4; cc++) {
        int br = brbase + cc;
        uint2 pv;
        pv.x = pack2(c0v[cc], c1v[cc]);
        pv.y = pack2(c2v[cc], c3v[cc]);
        *(uint2*)(BsB + br * 80 + (((kg ^ (br >> 2)) & 3) << 4) + kb) = pv;
      }
    }
  };

  const int NK = HID / 32;  // 64
  LOADT();
  STORET();
  LOADT();
  __syncthreads();

  for (int t = 0; t < NK; ++t) {
    half8 af[4];
    #pragma unroll
    for (int mi = 0; mi < 4; mi++) {
      int r = (wm << 6) + (mi << 4) + fr;
      af[mi] = *(half8*)(AsB + r * 80 + (((hi ^ (r >> 2)) & 3) << 4));
    }
    #pragma unroll
    for (int ni = 0; ni < 3; ni++) {
      int ng = (wn * 48) + (ni << 4) + fr;
      int nu = ng + 96;
      half8 bg = *(half8*)(BsB + ng * 80 + (((hi ^ (ng >> 2)) & 3) << 4));
      half8 bu = *(half8*)(BsB + nu * 80 + (((hi ^ (nu >> 2)) & 3) << 4));
      #pragma unroll
      for (int mi = 0; mi < 4; mi++) {
        accg[mi][ni] = __builtin_amdgcn_mfma_f32_16x16x32_f16(af[mi], bg, accg[mi][ni], 0, 0, 0);
        accu[mi][ni] = __builtin_amdgcn_mfma_f32_16x16x32_f16(af[mi], bu, accu[mi][ni], 0, 0, 0);
      }
    }
    __syncthreads();
    if (t + 1 < NK) {
      STORET();
      if (t + 2 < NK) LOADT();
      __syncthreads();
    }
  }

  #pragma unroll
  for (int mi = 0; mi < 4; mi++) {
    #pragma unroll
    for (int ni = 0; ni < 3; ni++) {
      int col = c0 + wn * 48 + (ni << 4) + fr;
      #pragma unroll
      for (int r = 0; r < 4; r++) {
        int rr = (wm << 6) + (mi << 4) + (hi << 2) + r;
        if (rr < ne) {
          float g = accg[mi][ni][r];
          float u = accu[mi][ni][r];
          float s = g / (1.f + __expf(-g)) * u;
          act[(size_t)(r0 + rr) * IMED + col] = f2h(s);
        }
      }
    }
  }
}

// ---------------- grouped down GEMM -> f16 scratch (no atomics) ------------
// BM=256, BN=256, BK=32, 512 threads (8 waves 4m x 2n), R5 schedule
__global__ __launch_bounds__(512, 2) void down_kernel(
    const u16* __restrict__ act, const float* __restrict__ Wd,
    const int* __restrict__ off, const int* __restrict__ cnt,
    const float* __restrict__ row_w, u16* __restrict__ dscr) {
  int bid = blockIdx.x;                 // 512 blocks
  int xcd = bid & 7, s2 = bid >> 3;
  int e = xcd + ((s2 & 7) << 3);
  int slab = s2 >> 3;                   // 0..7
  int r0 = off[e];
  int ne = cnt[e];
  int n0 = slab << 8;

  __shared__ __align__(16) char AsB[256 * 80];  // 20KB
  __shared__ __align__(16) char BsB[256 * 80];  // 20KB

  int tid = threadIdx.x;
  int lane = tid & 63;
  int wid = tid >> 6;
  int wm = wid >> 1, wn = wid & 1;
  int fr = lane & 15, hi = lane >> 4;

  int arow = tid >> 1, aseg = tid & 1;
  const u16* ap = act + (size_t)(r0 + ((arow < ne) ? arow : 0)) * IMED + (aseg << 4);
  int axr = (arow >> 2) & 3;

  int cq = tid & 63, kq = tid >> 6;
  int bcol = cq << 2;
  const float* wb = Wd + (size_t)e * ((size_t)IMED * HID) + (size_t)(kq << 2) * HID + n0 + bcol;

  f32x4 acc[4][8];
  #pragma unroll
  for (int a = 0; a < 4; a++)
    #pragma unroll
    for (int b = 0; b < 8; b++) acc[a][b] = (f32x4)0.f;

  uint4 qa0, qa1;
  float4 w0, w1, w2, w3;
  auto LOADT = [&]() {
    const uint4* p = (const uint4*)ap;
    qa0 = p[0]; qa1 = p[1];
    ap += 32;
    w0 = *(const float4*)(wb);
    w1 = *(const float4*)(wb + HID);
    w2 = *(const float4*)(wb + 2 * HID);
    w3 = *(const float4*)(wb + 3 * HID);
    wb += (size_t)32 * HID;
  };
  auto STORET = [&]() {
    char* A_ = AsB + arow * 80;
    int g0 = aseg << 1;
    *(uint4*)(A_ + (((g0 + 0) ^ axr) << 4)) = qa0;
    *(uint4*)(A_ + (((g0 + 1) ^ axr) << 4)) = qa1;
    float c0v[4] = {w0.x, w0.y, w0.z, w0.w};
    float c1v[4] = {w1.x, w1.y, w1.z, w1.w};
    float c2v[4] = {w2.x, w2.y, w2.z, w2.w};
    float c3v[4] = {w3.x, w3.y, w3.z, w3.w};
    int kg = kq >> 1, kb = (kq & 1) << 3;
    #pragma unroll
    for (int cc = 0; cc < 4; cc++) {
      int br = bcol + cc;
      uint2 pv;
      pv.x = pack2(c0v[cc], c1v[cc]);
      pv.y = pack2(c2v[cc], c3v[cc]);
      *(uint2*)(BsB + br * 80 + (((kg ^ (br >> 2)) & 3) << 4) + kb) = pv;
    }
  };

  const int NK = IMED / 32;  // 24
  LOADT();
  STORET();
  LOADT();
  __syncthreads();

  for (int t = 0; t < NK; ++t) {
    half8 af[4];
    #pragma unroll
    for (int mi = 0; mi < 4; mi++) {
      int r = (wm << 6) + (mi << 4) + fr;
      af[mi] = *(half8*)(AsB + r * 80 + (((hi ^ (r >> 2)) & 3) << 4));
    }
    #pragma unroll
    for (int ni = 0; ni < 8; ni++) {
      int n = (wn << 7) + (ni << 4) + fr;
      half8 bf_ = *(half8*)(BsB + n * 80 + (((hi ^ (n >> 2)) & 3) << 4));
      #pragma unroll
      for (int mi = 0; mi < 4; mi++)
        acc[mi][ni] = __builtin_amdgcn_mfma_f32_16x16x32_f16(af[mi], bf_, acc[mi][ni], 0, 0, 0);
    }
    __syncthreads();
    if (t + 1 < NK) {
      STORET();
      if (t + 2 < NK) LOADT();
      __syncthreads();
    }
  }

  #pragma unroll
  for (int mi = 0; mi < 4; mi++) {
    #pragma unroll
    for (int r = 0; r < 4; r++) {
      int rr = (wm << 6) + (mi << 4) + (hi << 2) + r;
      if (rr < ne) {
        float w = row_w[r0 + rr];
        #pragma unroll
        for (int ni = 0; ni < 8; ni++) {
          int col = n0 + (wn << 7) + (ni << 4) + fr;
          dscr[(size_t)(r0 + rr) * HID + col] = f2h(acc[mi][ni][r] * w);
        }
      }
    }
  }
}

// ---------------- combine: out[t] = sum_k dscr[inv[t*8+k]] ------------------
__global__ __launch_bounds__(256) void combine_kernel(
    const u16* __restrict__ dscr, const int* __restrict__ inv,
    float* __restrict__ out) {
  int t = blockIdx.x;
  int c0 = threadIdx.x << 3;  // 8 cols per thread
  int rows[TOPK];
  #pragma unroll
  for (int k = 0; k < TOPK; k++) rows[k] = inv[t * TOPK + k];
  float s[8] = {0.f, 0.f, 0.f, 0.f, 0.f, 0.f, 0.f, 0.f};
  #pragma unroll
  for (int k = 0; k < TOPK; k++) {
    union { uint4 q; _Float16 h[8]; } u;
    u.q = *(const uint4*)(dscr + (size_t)rows[k] * HID + c0);
    #pragma unroll
    for (int j = 0; j < 8; j++) s[j] += (float)u.h[j];
  }
  float4 o0 = {s[0], s[1], s[2], s[3]};
  float4 o1 = {s[4], s[5], s[6], s[7]};
  *(float4*)(out + (size_t)t * HID + c0) = o0;
  *(float4*)(out + (size_t)t * HID + c0 + 4) = o1;
}

// ---------------- launch ----------------
extern "C" void kernel_launch(void* const* d_in, const int* in_sizes, int n_in,
                              void* d_out, int out_size, void* d_ws, size_t ws_size,
                              hipStream_t stream) {
  const float* x = (const float*)d_in[0];
  const float* gw = (const float*)d_in[1];
  const float* wgu = (const float*)d_in[2];
  const float* wd = (const float*)d_in[3];
  float* out = (float*)d_out;
  char* ws = (char*)d_ws;

  int* cnt = (int*)(ws + 0);
  int* off = (int*)(ws + 512);
  int* topk_id = (int*)(ws + 1024);
  float* topk_w = (float*)(ws + 1024 + 32768);
  int* row_tok = (int*)(ws + 1024 + 65536);
  float* row_w = (float*)(ws + 1024 + 98304);
  u16* act = (u16*)(ws + 135168);                                   // 12.6 MB
  u16* xh = (u16*)(ws + 135168 + 12582912);                         // 4 MB
  int* inv = (int*)(ws + 135168 + 12582912 + 4194304);              // 32 KB
  u16* dscr = (u16*)(ws + 135168 + 12582912 + 4194304 + 32768);     // 33.5 MB

  hipMemsetAsync(cnt, 0, 256, stream);
  router_kernel<<<TOK / 4, 256, 0, stream>>>(x, gw, topk_id, topk_w, xh, cnt);
  scatter_kernel<<<NEXP, 256, 0, stream>>>(topk_id, topk_w, cnt, off, row_tok, row_w, inv);
  gateup_kernel<<<512, 512, 0, stream>>>(xh, wgu, off, cnt, row_tok, act);
  down_kernel<<<512, 512, 0, stream>>>(act, wd, off, cnt, row_w, dscr);
  combine_kernel<<<TOK, 256, 0, stream>>>(dscr, inv, out);
}

// Round 8
// 364.722 us; speedup vs baseline: 1.1654x; 1.0923x over previous
//
#include <hip/hip_runtime.h>
#include <hip/hip_bf16.h>
#include <hip/hip_fp16.h>

typedef unsigned int uint32;
typedef unsigned short u16;

#define TOK 1024
#define HID 2048
#define NEXP 64
#define TOPK 8
#define IMED 768
#define IMED2 1536

typedef __attribute__((ext_vector_type(8))) _Float16 half8;
typedef __attribute__((ext_vector_type(4))) float f32x4;

static __device__ __forceinline__ uint32 pack2(float a, float b) {
  union { _Float16 h[2]; uint32 u; } p;
  p.h[0] = (_Float16)a; p.h[1] = (_Float16)b;
  return p.u;
}
static __device__ __forceinline__ u16 f2h(float a) {
  union { _Float16 h; u16 u; } p;
  p.h = (_Float16)a;
  return p.u;
}

// ---------------- router: logits -> top8 -> renorm; emits xh ----------------
__global__ __launch_bounds__(256) void router_kernel(
    const float* __restrict__ x, const float* __restrict__ gw,
    int* __restrict__ topk_id, float* __restrict__ topk_w,
    u16* __restrict__ xh) {
  int t0 = blockIdx.x << 2;
  __shared__ float part[4][NEXP][5];
  int tid = threadIdx.x;
  int e = tid & 63, p = tid >> 6;
  const float* gwp = gw + (size_t)e * HID + (p << 9);
  const float* xp = x + (size_t)t0 * HID + (p << 9);
  float acc[4] = {0.f, 0.f, 0.f, 0.f};
  for (int i = 0; i < 128; i++) {
    float4 w = ((const float4*)gwp)[i];
    #pragma unroll
    for (int t = 0; t < 4; t++) {
      float4 xv = *(const float4*)(xp + (size_t)t * HID + (i << 2));
      acc[t] += w.x * xv.x + w.y * xv.y + w.z * xv.z + w.w * xv.w;
    }
  }
  #pragma unroll
  for (int t = 0; t < 4; t++) part[p][e][t] = acc[t];
  for (int i = tid; i < 2048; i += 256) {
    int r = i >> 9;
    int c = i & 511;
    float4 v = *(const float4*)(x + (size_t)(t0 + r) * HID + (c << 2));
    uint2 hp;
    hp.x = pack2(v.x, v.y);
    hp.y = pack2(v.z, v.w);
    *(uint2*)(xh + (size_t)(t0 + r) * HID + (c << 2)) = hp;
  }
  __syncthreads();
  int wv = tid >> 6, l = tid & 63;
  int t = t0 + wv;
  float lg = part[0][l][wv] + part[1][l][wv] + part[2][l][wv] + part[3][l][wv];
  float m = lg;
  #pragma unroll
  for (int d = 1; d < 64; d <<= 1) m = fmaxf(m, __shfl_xor(m, d));
  float v = __expf(lg - m);
  float w8[TOPK]; int i8[TOPK]; float wsum = 0.f;
  #pragma unroll
  for (int k = 0; k < TOPK; k++) {
    float bv = v; int bi = l;
    #pragma unroll
    for (int d = 1; d < 64; d <<= 1) {
      float ov = __shfl_xor(bv, d);
      int oi = __shfl_xor(bi, d);
      if (ov > bv || (ov == bv && oi < bi)) { bv = ov; bi = oi; }
    }
    w8[k] = bv; i8[k] = bi; wsum += bv;
    if (l == bi) v = -1.f;
  }
  if (l == 0) {
    float rinv = 1.f / wsum;
    #pragma unroll
    for (int k = 0; k < TOPK; k++) {
      topk_id[t * TOPK + k] = i8[k];
      topk_w[t * TOPK + k] = w8[k] * rinv;
    }
  }
}

// ------- per-expert scatter (64 blocks), self-counting, no memset ----------
__global__ __launch_bounds__(256) void scatter_kernel(
    const int* __restrict__ topk_id, const float* __restrict__ topk_w,
    int* __restrict__ off, int* __restrict__ gcnt,
    int* __restrict__ row_tok, float* __restrict__ row_w,
    int* __restrict__ inv) {
  int e = blockIdx.x;
  __shared__ int lcnt[NEXP];
  __shared__ int sbase;
  __shared__ int scur;
  int tid = threadIdx.x;
  if (tid < NEXP) lcnt[tid] = 0;
  __syncthreads();
  for (int i = tid; i < TOK * TOPK; i += 256) atomicAdd(&lcnt[topk_id[i]], 1);
  __syncthreads();
  if (tid < 64) {
    int c = lcnt[tid];
    int xv = c;
    #pragma unroll
    for (int d = 1; d < 64; d <<= 1) {
      int y = __shfl_up(xv, d);
      if (tid >= d) xv += y;
    }
    if (tid == e) {
      sbase = xv - c;
      off[e] = xv - c;
      gcnt[e] = c;
    }
    if (tid == 0) scur = 0;
  }
  __syncthreads();
  int base = sbase;
  for (int i = tid; i < TOK * TOPK; i += 256) {
    if (topk_id[i] == e) {
      int p = atomicAdd(&scur, 1);
      row_tok[base + p] = i >> 3;
      row_w[base + p] = topk_w[i];
      inv[i] = base + p;
    }
  }
}

// ---------------- grouped gate_up GEMM + fused SwiGLU (R5 schedule) --------
// BM=256, BN=96 gate + 96 up, BK=32, 512 threads (8 waves 4m x 2n)
// single LDS buffer, 1-deep register prefetch, XCD-bijective block remap
__global__ __launch_bounds__(512, 2) void gateup_kernel(
    const u16* __restrict__ xh, const float* __restrict__ Wgu,
    const int* __restrict__ off, const int* __restrict__ cnt,
    const int* __restrict__ row_tok, u16* __restrict__ act) {
  int bid = blockIdx.x;                 // 512 blocks
  int xcd = bid & 7, s2 = bid >> 3;
  int e = xcd + ((s2 & 7) << 3);        // all slabs of expert e on one XCD
  int slab = s2 >> 3;                   // 0..7
  int r0 = off[e];
  int ne = cnt[e];
  int c0 = slab * 96;

  __shared__ __align__(16) char AsB[256 * 80];  // 20KB
  __shared__ __align__(16) char BsB[192 * 80];  // 15KB

  int tid = threadIdx.x;
  int lane = tid & 63;
  int wid = tid >> 6;
  int wm = wid >> 1, wn = wid & 1;      // 4m x 2n
  int fr = lane & 15, hi = lane >> 4;

  int arow = tid >> 1, aseg = tid & 1;
  int tok = row_tok[r0 + ((arow < ne) ? arow : 0)];
  const u16* xa = xh + (size_t)tok * HID + (aseg << 4);
  int axr = (arow >> 2) & 3;

  bool bact = tid < 384;
  int cg = tid % 24, h = (tid / 24) & 1, kq = tid / 48;  // kq 0..7
  int bcol = cg << 2;
  int gc = h ? (IMED + c0 + bcol) : (c0 + bcol);
  const float* wb = Wgu + (size_t)e * ((size_t)HID * IMED2) + (size_t)(kq << 2) * IMED2 + gc;
  int brbase = 96 * h + bcol;

  f32x4 accg[4][3], accu[4][3];
  #pragma unroll
  for (int a = 0; a < 4; a++)
    #pragma unroll
    for (int b = 0; b < 3; b++) { accg[a][b] = (f32x4)0.f; accu[a][b] = (f32x4)0.f; }

  uint4 qa0, qa1;
  float4 w0, w1, w2, w3;
  auto LOADT = [&]() {
    const uint4* p = (const uint4*)xa;
    qa0 = p[0]; qa1 = p[1];
    xa += 32;
    if (bact) {
      w0 = *(const float4*)(wb);
      w1 = *(const float4*)(wb + IMED2);
      w2 = *(const float4*)(wb + 2 * IMED2);
      w3 = *(const float4*)(wb + 3 * IMED2);
    }
    wb += (size_t)32 * IMED2;
  };
  auto STORET = [&]() {
    char* A_ = AsB + arow * 80;
    int g0 = aseg << 1;
    *(uint4*)(A_ + (((g0 + 0) ^ axr) << 4)) = qa0;
    *(uint4*)(A_ + (((g0 + 1) ^ axr) << 4)) = qa1;
    if (bact) {
      float c0v[4] = {w0.x, w0.y, w0.z, w0.w};
      float c1v[4] = {w1.x, w1.y, w1.z, w1.w};
      float c2v[4] = {w2.x, w2.y, w2.z, w2.w};
      float c3v[4] = {w3.x, w3.y, w3.z, w3.w};
      int kg = kq >> 1, kb = (kq & 1) << 3;
      #pragma unroll
      for (int cc = 0; cc < 4; cc++) {
        int br = brbase + cc;
        uint2 pv;
        pv.x = pack2(c0v[cc], c1v[cc]);
        pv.y = pack2(c2v[cc], c3v[cc]);
        *(uint2*)(BsB + br * 80 + (((kg ^ (br >> 2)) & 3) << 4) + kb) = pv;
      }
    }
  };

  const int NK = HID / 32;  // 64
  LOADT();
  STORET();
  LOADT();
  __syncthreads();

  for (int t = 0; t < NK; ++t) {
    half8 af[4];
    #pragma unroll
    for (int mi = 0; mi < 4; mi++) {
      int r = (wm << 6) + (mi << 4) + fr;
      af[mi] = *(half8*)(AsB + r * 80 + (((hi ^ (r >> 2)) & 3) << 4));
    }
    #pragma unroll
    for (int ni = 0; ni < 3; ni++) {
      int ng = (wn * 48) + (ni << 4) + fr;
      int nu = ng + 96;
      half8 bg = *(half8*)(BsB + ng * 80 + (((hi ^ (ng >> 2)) & 3) << 4));
      half8 bu = *(half8*)(BsB + nu * 80 + (((hi ^ (nu >> 2)) & 3) << 4));
      #pragma unroll
      for (int mi = 0; mi < 4; mi++) {
        accg[mi][ni] = __builtin_amdgcn_mfma_f32_16x16x32_f16(af[mi], bg, accg[mi][ni], 0, 0, 0);
        accu[mi][ni] = __builtin_amdgcn_mfma_f32_16x16x32_f16(af[mi], bu, accu[mi][ni], 0, 0, 0);
      }
    }
    __syncthreads();
    if (t + 1 < NK) {
      STORET();
      if (t + 2 < NK) LOADT();
      __syncthreads();
    }
  }

  #pragma unroll
  for (int mi = 0; mi < 4; mi++) {
    #pragma unroll
    for (int ni = 0; ni < 3; ni++) {
      int col = c0 + wn * 48 + (ni << 4) + fr;
      #pragma unroll
      for (int r = 0; r < 4; r++) {
        int rr = (wm << 6) + (mi << 4) + (hi << 2) + r;
        if (rr < ne) {
          float g = accg[mi][ni][r];
          float u = accu[mi][ni][r];
          float s = g / (1.f + __expf(-g)) * u;
          act[(size_t)(r0 + rr) * IMED + col] = f2h(s);
        }
      }
    }
  }
}

// ---------------- grouped down GEMM -> f16 scratch (no atomics) ------------
// BM=256, BN=256, BK=32, 512 threads (8 waves 4m x 2n), R5 schedule
__global__ __launch_bounds__(512, 2) void down_kernel(
    const u16* __restrict__ act, const float* __restrict__ Wd,
    const int* __restrict__ off, const int* __restrict__ cnt,
    const float* __restrict__ row_w, u16* __restrict__ dscr) {
  int bid = blockIdx.x;                 // 512 blocks
  int xcd = bid & 7, s2 = bid >> 3;
  int e = xcd + ((s2 & 7) << 3);
  int slab = s2 >> 3;                   // 0..7
  int r0 = off[e];
  int ne = cnt[e];
  int n0 = slab << 8;

  __shared__ __align__(16) char AsB[256 * 80];  // 20KB
  __shared__ __align__(16) char BsB[256 * 80];  // 20KB

  int tid = threadIdx.x;
  int lane = tid & 63;
  int wid = tid >> 6;
  int wm = wid >> 1, wn = wid & 1;
  int fr = lane & 15, hi = lane >> 4;

  int arow = tid >> 1, aseg = tid & 1;
  const u16* ap = act + (size_t)(r0 + ((arow < ne) ? arow : 0)) * IMED + (aseg << 4);
  int axr = (arow >> 2) & 3;

  int cq = tid & 63, kq = tid >> 6;
  int bcol = cq << 2;
  const float* wb = Wd + (size_t)e * ((size_t)IMED * HID) + (size_t)(kq << 2) * HID + n0 + bcol;

  f32x4 acc[4][8];
  #pragma unroll
  for (int a = 0; a < 4; a++)
    #pragma unroll
    for (int b = 0; b < 8; b++) acc[a][b] = (f32x4)0.f;

  uint4 qa0, qa1;
  float4 w0, w1, w2, w3;
  auto LOADT = [&]() {
    const uint4* p = (const uint4*)ap;
    qa0 = p[0]; qa1 = p[1];
    ap += 32;
    w0 = *(const float4*)(wb);
    w1 = *(const float4*)(wb + HID);
    w2 = *(const float4*)(wb + 2 * HID);
    w3 = *(const float4*)(wb + 3 * HID);
    wb += (size_t)32 * HID;
  };
  auto STORET = [&]() {
    char* A_ = AsB + arow * 80;
    int g0 = aseg << 1;
    *(uint4*)(A_ + (((g0 + 0) ^ axr) << 4)) = qa0;
    *(uint4*)(A_ + (((g0 + 1) ^ axr) << 4)) = qa1;
    float c0v[4] = {w0.x, w0.y, w0.z, w0.w};
    float c1v[4] = {w1.x, w1.y, w1.z, w1.w};
    float c2v[4] = {w2.x, w2.y, w2.z, w2.w};
    float c3v[4] = {w3.x, w3.y, w3.z, w3.w};
    int kg = kq >> 1, kb = (kq & 1) << 3;
    #pragma unroll
    for (int cc = 0; cc < 4; cc++) {
      int br = bcol + cc;
      uint2 pv;
      pv.x = pack2(c0v[cc], c1v[cc]);
      pv.y = pack2(c2v[cc], c3v[cc]);
      *(uint2*)(BsB + br * 80 + (((kg ^ (br >> 2)) & 3) << 4) + kb) = pv;
    }
  };

  const int NK = IMED / 32;  // 24
  LOADT();
  STORET();
  LOADT();
  __syncthreads();

  for (int t = 0; t < NK; ++t) {
    half8 af[4];
    #pragma unroll
    for (int mi = 0; mi < 4; mi++) {
      int r = (wm << 6) + (mi << 4) + fr;
      af[mi] = *(half8*)(AsB + r * 80 + (((hi ^ (r >> 2)) & 3) << 4));
    }
    #pragma unroll
    for (int ni = 0; ni < 8; ni++) {
      int n = (wn << 7) + (ni << 4) + fr;
      half8 bf_ = *(half8*)(BsB + n * 80 + (((hi ^ (n >> 2)) & 3) << 4));
      #pragma unroll
      for (int mi = 0; mi < 4; mi++)
        acc[mi][ni] = __builtin_amdgcn_mfma_f32_16x16x32_f16(af[mi], bf_, acc[mi][ni], 0, 0, 0);
    }
    __syncthreads();
    if (t + 1 < NK) {
      STORET();
      if (t + 2 < NK) LOADT();
      __syncthreads();
    }
  }

  #pragma unroll
  for (int mi = 0; mi < 4; mi++) {
    #pragma unroll
    for (int r = 0; r < 4; r++) {
      int rr = (wm << 6) + (mi << 4) + (hi << 2) + r;
      if (rr < ne) {
        float w = row_w[r0 + rr];
        #pragma unroll
        for (int ni = 0; ni < 8; ni++) {
          int col = n0 + (wn << 7) + (ni << 4) + fr;
          dscr[(size_t)(r0 + rr) * HID + col] = f2h(acc[mi][ni][r] * w);
        }
      }
    }
  }
}

// ---------------- combine: out[t] = sum_k dscr[inv[t*8+k]] ------------------
__global__ __launch_bounds__(256) void combine_kernel(
    const u16* __restrict__ dscr, const int* __restrict__ inv,
    float* __restrict__ out) {
  int t = blockIdx.x;
  int c0 = threadIdx.x << 3;  // 8 cols per thread
  int rows[TOPK];
  #pragma unroll
  for (int k = 0; k < TOPK; k++) rows[k] = inv[t * TOPK + k];
  float s[8] = {0.f, 0.f, 0.f, 0.f, 0.f, 0.f, 0.f, 0.f};
  #pragma unroll
  for (int k = 0; k < TOPK; k++) {
    union { uint4 q; _Float16 h[8]; } u;
    u.q = *(const uint4*)(dscr + (size_t)rows[k] * HID + c0);
    #pragma unroll
    for (int j = 0; j < 8; j++) s[j] += (float)u.h[j];
  }
  float4 o0 = {s[0], s[1], s[2], s[3]};
  float4 o1 = {s[4], s[5], s[6], s[7]};
  *(float4*)(out + (size_t)t * HID + c0) = o0;
  *(float4*)(out + (size_t)t * HID + c0 + 4) = o1;
}

// ---------------- launch ----------------
extern "C" void kernel_launch(void* const* d_in, const int* in_sizes, int n_in,
                              void* d_out, int out_size, void* d_ws, size_t ws_size,
                              hipStream_t stream) {
  const float* x = (const float*)d_in[0];
  const float* gw = (const float*)d_in[1];
  const float* wgu = (const float*)d_in[2];
  const float* wd = (const float*)d_in[3];
  float* out = (float*)d_out;
  char* ws = (char*)d_ws;

  int* gcnt = (int*)(ws + 0);
  int* off = (int*)(ws + 512);
  int* topk_id = (int*)(ws + 1024);
  float* topk_w = (float*)(ws + 1024 + 32768);
  int* row_tok = (int*)(ws + 1024 + 65536);
  float* row_w = (float*)(ws + 1024 + 98304);
  u16* act = (u16*)(ws + 135168);                                   // 12.6 MB
  u16* xh = (u16*)(ws + 135168 + 12582912);                         // 4 MB
  int* inv = (int*)(ws + 135168 + 12582912 + 4194304);              // 32 KB
  u16* dscr = (u16*)(ws + 135168 + 12582912 + 4194304 + 32768);     // 33.5 MB

  router_kernel<<<TOK / 4, 256, 0, stream>>>(x, gw, topk_id, topk_w, xh);
  scatter_kernel<<<NEXP, 256, 0, stream>>>(topk_id, topk_w, off, gcnt, row_tok, row_w, inv);
  gateup_kernel<<<512, 512, 0, stream>>>(xh, wgu, off, gcnt, row_tok, act);
  down_kernel<<<512, 512, 0, stream>>>(act, wd, off, gcnt, row_w, dscr);
  combine_kernel<<<TOK, 256, 0, stream>>>(dscr, inv, out);
}